// Round 1
// baseline (10227.352 us; speedup 1.0000x reference)
//
#include <hip/hip_runtime.h>
#include <hip/hip_fp16.h>

// Problem dims
#define BB   128
#define TT   512
#define INS  64
#define HH   512
#define K0   576    // INS + HH (layer0 fused [x | h1] GEMM depth)
#define K1   1024   // HH + HH  (layer1 fused [h1 | h2] GEMM depth)
#define PAD0 584    // K0 + 8 (LDS bank-conflict pad, keeps 16B alignment)
#define PAD1 1032   // K1 + 8
#define NWG  128
#define H2   256

typedef _Float16 f16;
typedef f16 f16x8 __attribute__((ext_vector_type(8)));
typedef float f32x4 __attribute__((ext_vector_type(4)));

__device__ __forceinline__ float sigmoidf_(float x) {
  return 1.0f / (1.0f + __expf(-x));
}
__device__ __forceinline__ float tanhf_(float x) {
  // overflow-safe: exp->inf gives 1-0=1; exp->0 gives 1-2=-1
  return 1.0f - 2.0f / (__expf(2.0f * x) + 1.0f);
}

// Persistent fused 2-layer LSTM.
// Grid: 128 WGs x 256 threads. WG = (mg in 0..1, ng in 0..63).
// WG owns M-rows mg*64..+64 and h-columns ng*8..+8 (both layers).
// waves 0,1 -> layer0 (rows +0/+32), waves 2,3 -> layer1.
// Superstep s: L0 computes h1_s (s<T), L1 computes h2_{s-1} (s>=1). 513 supersteps.
__global__ __launch_bounds__(256, 1) void lstm_fused(
    const float* __restrict__ x,
    const float* __restrict__ Wih0, const float* __restrict__ Whh0,
    const float* __restrict__ bih0, const float* __restrict__ bhh0,
    const float* __restrict__ Wih1, const float* __restrict__ Whh1,
    const float* __restrict__ bih1, const float* __restrict__ bhh1,
    int* __restrict__ bar, f16* __restrict__ h1buf, f16* __restrict__ h2buf)
{
  extern __shared__ f16 smem[];
  f16* W0s = smem;                 // [32][PAD0]
  f16* W1s = smem + 32 * PAD0;     // [32][PAD1]

  const int tid  = threadIdx.x;
  const int wg   = blockIdx.x;
  const int mg   = wg >> 6;
  const int ng   = wg & 63;
  const int wid  = tid >> 6;
  const int lane = tid & 63;

  // ---- weights -> LDS (fp16), once ----
  // LDS row r = q*8+j  ->  global gate row g = q*512 + ng*8 + j  (q: 0=i,1=f,2=g,3=o)
  for (int e = tid; e < 32 * K0; e += 256) {
    int r = e / K0, k = e - r * K0;
    int g = ((r >> 3) << 9) + (ng << 3) + (r & 7);
    float v = (k < INS) ? Wih0[g * INS + k] : Whh0[g * HH + (k - INS)];
    W0s[r * PAD0 + k] = (f16)v;
  }
  for (int e = tid; e < 32 * K1; e += 256) {
    int r = e >> 10, k = e & (K1 - 1);
    int g = ((r >> 3) << 9) + (ng << 3) + (r & 7);
    float v = (k < HH) ? Wih1[g * HH + k] : Whh1[g * HH + (k - HH)];
    W1s[r * PAD1 + k] = (f16)v;
  }

  const bool isL1 = (wid >= 2);
  const int  wrow = mg * 64 + (isL1 ? (wid - 2) : wid) * 32;  // wave M base
  const int  col0 = lane & 15;       // fragment column (N within frag)
  const int  rA   = lane & 15;       // A-row within fragment
  const int  kq   = (lane >> 4) * 8; // k sub-offset within a 32-wide k-step
  const int  hcol = (ng << 3) + (lane & 7);
  const bool low  = (lane & 8) == 0; // lanes holding i (frag0) / g (frag1)

  // per-lane bias for the wave's two N-frags (constant over steps/rows)
  float bias[2];
  #pragma unroll
  for (int n = 0; n < 2; n++) {
    int c = n * 16 + col0;
    int g = ((c >> 3) << 9) + (ng << 3) + (c & 7);
    bias[n] = isL1 ? (bih1[g] + bhh1[g]) : (bih0[g] + bhh0[g]);
  }
  __syncthreads();

  f32x4 cst[2] = {};  // cell state, valid in low lanes

  for (int s = 0; s <= TT; ++s) {
    const f16* h1r = h1buf + ((s + 1) & 1) * (BB * HH); // h1_{s-1}
    f16*       h1w = h1buf + ((s    ) & 1) * (BB * HH); // h1_s
    const f16* h2r = h2buf + ((s    ) & 1) * (BB * HH); // h2_{s-2}
    f16*       h2w = h2buf + ((s + 1) & 1) * (BB * HH); // h2_{s-1}

    if (!isL1 && s < TT) {
      // ---- layer0: gates = [x_s | h1_{s-1}] @ [Wih0 | Whh0]^T ----
      f32x4 acc[2][2] = {};
      #pragma unroll
      for (int ks = 0; ks < K0 / 32; ++ks) {
        const int kk = ks * 32 + kq;
        f16x8 a[2];
        #pragma unroll
        for (int m = 0; m < 2; m++) {
          const int row = wrow + m * 16 + rA;
          if (ks < INS / 32) {  // compile-time: x part (fp32 -> fp16)
            const float4* xp = reinterpret_cast<const float4*>(
                x + ((size_t)row * TT + (size_t)s) * INS + kk);
            float4 q0 = xp[0], q1 = xp[1];
            f16x8 av;
            av[0]=(f16)q0.x; av[1]=(f16)q0.y; av[2]=(f16)q0.z; av[3]=(f16)q0.w;
            av[4]=(f16)q1.x; av[5]=(f16)q1.y; av[6]=(f16)q1.z; av[7]=(f16)q1.w;
            a[m] = av;
          } else {
            a[m] = *reinterpret_cast<const f16x8*>(h1r + row * HH + (kk - INS));
          }
        }
        #pragma unroll
        for (int n = 0; n < 2; n++) {
          f16x8 b = *reinterpret_cast<const f16x8*>(&W0s[(n * 16 + col0) * PAD0 + kk]);
          acc[0][n] = __builtin_amdgcn_mfma_f32_16x16x32_f16(a[0], b, acc[0][n], 0, 0, 0);
          acc[1][n] = __builtin_amdgcn_mfma_f32_16x16x32_f16(a[1], b, acc[1][n], 0, 0, 0);
        }
      }
      // ---- LSTM cell (frag0 = [i|f], frag1 = [g|o]) ----
      #pragma unroll
      for (int m = 0; m < 2; m++) {
        float res[4];
        #pragma unroll
        for (int j = 0; j < 4; j++) {
          float v0 = acc[m][0][j] + bias[0];
          float v1 = acc[m][1][j] + bias[1];
          float p0 = __shfl_xor(v0, 8, 64);
          float p1 = __shfl_xor(v1, 8, 64);
          float ip = low ? v0 : p0;
          float fp = low ? p0 : v0;
          float gp = low ? v1 : p1;
          float op = low ? p1 : v1;
          float cn = sigmoidf_(fp) * cst[m][j] + sigmoidf_(ip) * tanhf_(gp);
          cst[m][j] = cn;
          res[j] = sigmoidf_(op) * tanhf_(cn);
        }
        if (low) {
          const int rowb = wrow + m * 16 + ((lane >> 4) << 2);
          #pragma unroll
          for (int j = 0; j < 4; j++)
            h1w[(rowb + j) * HH + hcol] = (f16)res[j];
        }
      }
    } else if (isL1 && s >= 1) {
      // ---- layer1: gates = [h1_{s-1} | h2_{s-2}] @ [Wih1 | Whh1]^T ----
      f32x4 acc[2][2] = {};
      #pragma unroll
      for (int ks = 0; ks < K1 / 32; ++ks) {
        const int kk = ks * 32 + kq;
        f16x8 a[2];
        #pragma unroll
        for (int m = 0; m < 2; m++) {
          const int row = wrow + m * 16 + rA;
          if (ks < HH / 32) {
            a[m] = *reinterpret_cast<const f16x8*>(h1r + row * HH + kk);
          } else {
            a[m] = *reinterpret_cast<const f16x8*>(h2r + row * HH + (kk - HH));
          }
        }
        #pragma unroll
        for (int n = 0; n < 2; n++) {
          f16x8 b = *reinterpret_cast<const f16x8*>(&W1s[(n * 16 + col0) * PAD1 + kk]);
          acc[0][n] = __builtin_amdgcn_mfma_f32_16x16x32_f16(a[0], b, acc[0][n], 0, 0, 0);
          acc[1][n] = __builtin_amdgcn_mfma_f32_16x16x32_f16(a[1], b, acc[1][n], 0, 0, 0);
        }
      }
      #pragma unroll
      for (int m = 0; m < 2; m++) {
        float res[4];
        #pragma unroll
        for (int j = 0; j < 4; j++) {
          float v0 = acc[m][0][j] + bias[0];
          float v1 = acc[m][1][j] + bias[1];
          float p0 = __shfl_xor(v0, 8, 64);
          float p1 = __shfl_xor(v1, 8, 64);
          float ip = low ? v0 : p0;
          float fp = low ? p0 : v0;
          float gp = low ? v1 : p1;
          float op = low ? p1 : v1;
          float cn = sigmoidf_(fp) * cst[m][j] + sigmoidf_(ip) * tanhf_(gp);
          cst[m][j] = cn;
          res[j] = sigmoidf_(op) * tanhf_(cn);
        }
        if (low) {
          const int rowb = wrow + m * 16 + ((lane >> 4) << 2);
          #pragma unroll
          for (int j = 0; j < 4; j++)
            h2w[(rowb + j) * HH + hcol] = (f16)res[j];
        }
      }
    }

    // ---- grid barrier (sense-reversing, agent scope) ----
    __syncthreads();
    if (tid == 0) {
      int gen = __hip_atomic_load(bar + 1, __ATOMIC_RELAXED, __HIP_MEMORY_SCOPE_AGENT);
      int prev = __hip_atomic_fetch_add(bar, 1, __ATOMIC_ACQ_REL, __HIP_MEMORY_SCOPE_AGENT);
      if (prev == NWG - 1) {
        __hip_atomic_store(bar, 0, __ATOMIC_RELAXED, __HIP_MEMORY_SCOPE_AGENT);
        __hip_atomic_fetch_add(bar + 1, 1, __ATOMIC_RELEASE, __HIP_MEMORY_SCOPE_AGENT);
      } else {
        while (__hip_atomic_load(bar + 1, __ATOMIC_ACQUIRE, __HIP_MEMORY_SCOPE_AGENT) == gen) {
          __builtin_amdgcn_s_sleep(2);
        }
      }
    }
    __syncthreads();
  }
}

__global__ void fc1_kernel(const f16* __restrict__ last, const float* __restrict__ w,
                           const float* __restrict__ b, float* __restrict__ z) {
  const int bb = blockIdx.x;   // batch row
  const int j  = threadIdx.x;  // 0..255 output col
  const f16*   lp = last + bb * HH;
  const float* wp = w + j * HH;
  float s = b[j];
  #pragma unroll 8
  for (int k = 0; k < HH; k++) s += (float)lp[k] * wp[k];
  z[bb * H2 + j] = fmaxf(s, 0.0f);
}

__global__ void fc2_kernel(const float* __restrict__ z, const float* __restrict__ w,
                           const float* __restrict__ b, float* __restrict__ out) {
  const int bb = threadIdx.x;  // 0..127
  float s = b[0];
  #pragma unroll 8
  for (int k = 0; k < H2; k++) s += z[bb * H2 + k] * w[k];
  out[bb] = s;
}

extern "C" void kernel_launch(void* const* d_in, const int* in_sizes, int n_in,
                              void* d_out, int out_size, void* d_ws, size_t ws_size,
                              hipStream_t stream) {
  const float* x     = (const float*)d_in[0];
  const float* Wih0  = (const float*)d_in[1];
  const float* Whh0  = (const float*)d_in[2];
  const float* bih0  = (const float*)d_in[3];
  const float* bhh0  = (const float*)d_in[4];
  const float* Wih1  = (const float*)d_in[5];
  const float* Whh1  = (const float*)d_in[6];
  const float* bih1  = (const float*)d_in[7];
  const float* bhh1  = (const float*)d_in[8];
  const float* fc1w  = (const float*)d_in[9];
  const float* fc1b  = (const float*)d_in[10];
  const float* fc2w  = (const float*)d_in[11];
  const float* fc2b  = (const float*)d_in[12];

  char* ws = (char*)d_ws;
  int*  bar = (int*)ws;                          // 2 ints
  f16*  h1  = (f16*)(ws + 256);                  // 2 x B x H
  f16*  h2  = h1 + 2 * BB * HH;                  // 2 x B x H
  float* z  = (float*)(ws + 256 + (size_t)4 * BB * HH * sizeof(f16));  // B x H2

  // zero barrier + h buffers (h_{-1} = 0); re-run every replay
  hipMemsetAsync(ws, 0, 256 + (size_t)4 * BB * HH * sizeof(f16), stream);

  const size_t smem = (size_t)(32 * PAD0 + 32 * PAD1) * sizeof(f16);
  lstm_fused<<<NWG, 256, smem, stream>>>(x, Wih0, Whh0, bih0, bhh0,
                                         Wih1, Whh1, bih1, bhh1, bar, h1, h2);

  const f16* last = h2 + ((TT - 1) & 1) * (BB * HH);  // h2_{T-1}
  fc1_kernel<<<BB, 256, 0, stream>>>(last, fc1w, fc1b, z);
  fc2_kernel<<<1, BB, 0, stream>>>(z, fc2w, fc2b, (float*)d_out);
}

// Round 2
// 7166.306 us; speedup vs baseline: 1.4271x; 1.4271x over previous
//
#include <hip/hip_runtime.h>
#include <hip/hip_fp16.h>

// Problem dims
#define BB   128
#define TT   512
#define INS  64
#define HH   512
#define K0   576    // INS + HH (layer0 fused [x | h1] GEMM depth)
#define K1   1024   // HH + HH  (layer1 fused [h1 | h2] GEMM depth)
#define PAD0 584    // K0 + 8 (LDS pad; keeps 16B alignment, stride%32dw==4 -> 2-way max)
#define PAD1 1032   // K1 + 8
#define NWG  128
#define NTHR 512
#define H2   256

typedef _Float16 f16;
typedef f16 f16x4 __attribute__((ext_vector_type(4)));
typedef f16 f16x8 __attribute__((ext_vector_type(8)));
typedef float f32x4 __attribute__((ext_vector_type(4)));

__device__ __forceinline__ float sigmoidf_(float x) {
  return 1.0f / (1.0f + __expf(-x));
}
__device__ __forceinline__ float tanhf_(float x) {
  return 1.0f - 2.0f / (__expf(2.0f * x) + 1.0f);
}

// Persistent fused 2-layer LSTM.
// Grid: 128 WGs x 512 threads (8 waves). WG = (mg 0..1, ng 0..63):
// owns M-rows mg*64..+64 and h-columns ng*8..+8 (-> 32 gate rows) for BOTH layers.
// waves 0-3 -> layer0 (16 rows each), waves 4-7 -> layer1.
// Superstep s: L0 computes h1_s (s<T), L1 computes h2_{s-1} (s>=1). 513 supersteps.
__global__ __launch_bounds__(NTHR, 1) void lstm_fused(
    const float* __restrict__ x,
    const float* __restrict__ Wih0, const float* __restrict__ Whh0,
    const float* __restrict__ bih0, const float* __restrict__ bhh0,
    const float* __restrict__ Wih1, const float* __restrict__ Whh1,
    const float* __restrict__ bih1, const float* __restrict__ bhh1,
    int* __restrict__ bar, f16* __restrict__ h1buf, f16* __restrict__ h2buf)
{
  extern __shared__ f16 smem[];
  f16* W0s = smem;                 // [32][PAD0]
  f16* W1s = smem + 32 * PAD0;     // [32][PAD1]

  const int tid  = threadIdx.x;
  const int wg   = blockIdx.x;
  const int mg   = wg >> 6;
  const int ng   = wg & 63;
  const int wid  = tid >> 6;
  const int lane = tid & 63;

  // ---- weights -> LDS (fp16), vectorized float4, once ----
  // LDS row r = q*8+j -> global gate row g = q*512 + ng*8 + j (q: 0=i,1=f,2=g,3=o)
  for (int e4 = tid; e4 < 32 * (K0 / 4); e4 += NTHR) {
    int r = e4 / (K0 / 4), k = (e4 - r * (K0 / 4)) * 4;
    int g = ((r >> 3) << 9) + (ng << 3) + (r & 7);
    float4 v = (k < INS)
        ? *reinterpret_cast<const float4*>(Wih0 + g * INS + k)
        : *reinterpret_cast<const float4*>(Whh0 + g * HH + (k - INS));
    f16x4 h; h[0]=(f16)v.x; h[1]=(f16)v.y; h[2]=(f16)v.z; h[3]=(f16)v.w;
    *reinterpret_cast<f16x4*>(&W0s[r * PAD0 + k]) = h;
  }
  for (int e4 = tid; e4 < 32 * (K1 / 4); e4 += NTHR) {
    int r = e4 >> 8, k = (e4 & 255) * 4;
    int g = ((r >> 3) << 9) + (ng << 3) + (r & 7);
    float4 v = (k < HH)
        ? *reinterpret_cast<const float4*>(Wih1 + g * HH + k)
        : *reinterpret_cast<const float4*>(Whh1 + g * HH + (k - HH));
    f16x4 h; h[0]=(f16)v.x; h[1]=(f16)v.y; h[2]=(f16)v.z; h[3]=(f16)v.w;
    *reinterpret_cast<f16x4*>(&W1s[r * PAD1 + k]) = h;
  }

  const bool isL1 = (wid >= 4);
  const int  wrow = mg * 64 + (wid & 3) * 16;   // wave M base (16 rows)
  const int  col0 = lane & 15;        // fragment column (gate col within frag)
  const int  rA   = lane & 15;        // A-row within fragment
  const int  kq   = (lane >> 4) * 8;  // k sub-offset within a 32-wide k-step
  const int  hcol = (ng << 3) + (lane & 7);
  const bool low  = (lane & 8) == 0;  // lanes holding i (frag0) / g (frag1)

  float bias[2];
  #pragma unroll
  for (int n = 0; n < 2; n++) {
    int c = n * 16 + col0;
    int g = ((c >> 3) << 9) + (ng << 3) + (c & 7);
    bias[n] = isL1 ? (bih1[g] + bhh1[g]) : (bih0[g] + bhh0[g]);
  }
  __syncthreads();

  f32x4 cst = {};  // cell state (4 rows x 1 col per low lane)

  // tree-barrier pointers (256B-spaced lines)
  int* grp  = bar + (wg & 7) * 64;
  int* glob = bar + 512;
  int* genp = bar + 576;

  for (int s = 0; s <= TT; ++s) {
    const f16* h1r = h1buf + ((s + 1) & 1) * (BB * HH); // h1_{s-1}
    f16*       h1w = h1buf + ((s    ) & 1) * (BB * HH); // h1_s
    const f16* h2r = h2buf + ((s    ) & 1) * (BB * HH); // h2_{s-2}
    f16*       h2w = h2buf + ((s + 1) & 1) * (BB * HH); // h2_{s-1}

    const bool active = isL1 ? (s >= 1) : (s < TT);
    if (active) {
      const int row = wrow + rA;
      f32x4 acc0 = {}, acc1 = {};

      if (!isL1) {
        // ---- layer0: gates = [x_s | h1_{s-1}] @ [Wih0 | Whh0]^T ----
        const float* xb = x + ((size_t)row * TT + (size_t)s) * INS;
        #pragma unroll
        for (int ks = 0; ks < 2; ++ks) {
          const int kk = ks * 32 + kq;
          float4 q0 = *reinterpret_cast<const float4*>(xb + kk);
          float4 q1 = *reinterpret_cast<const float4*>(xb + kk + 4);
          f16x8 a;
          a[0]=(f16)q0.x; a[1]=(f16)q0.y; a[2]=(f16)q0.z; a[3]=(f16)q0.w;
          a[4]=(f16)q1.x; a[5]=(f16)q1.y; a[6]=(f16)q1.z; a[7]=(f16)q1.w;
          f16x8 b0 = *reinterpret_cast<const f16x8*>(&W0s[col0 * PAD0 + kk]);
          f16x8 b1 = *reinterpret_cast<const f16x8*>(&W0s[(16 + col0) * PAD0 + kk]);
          acc0 = __builtin_amdgcn_mfma_f32_16x16x32_f16(a, b0, acc0, 0, 0, 0);
          acc1 = __builtin_amdgcn_mfma_f32_16x16x32_f16(a, b1, acc1, 0, 0, 0);
        }
        #pragma unroll
        for (int c = 0; c < 2; ++c) {
          f16x8 a[8];
          #pragma unroll
          for (int u = 0; u < 8; ++u) {
            const int kh = (c * 8 + u) * 32 + kq;
            a[u] = *reinterpret_cast<const f16x8*>(h1r + row * HH + kh);
          }
          #pragma unroll
          for (int u = 0; u < 8; ++u) {
            const int kk = INS + (c * 8 + u) * 32 + kq;
            f16x8 b0 = *reinterpret_cast<const f16x8*>(&W0s[col0 * PAD0 + kk]);
            f16x8 b1 = *reinterpret_cast<const f16x8*>(&W0s[(16 + col0) * PAD0 + kk]);
            acc0 = __builtin_amdgcn_mfma_f32_16x16x32_f16(a[u], b0, acc0, 0, 0, 0);
            acc1 = __builtin_amdgcn_mfma_f32_16x16x32_f16(a[u], b1, acc1, 0, 0, 0);
          }
        }
      } else {
        // ---- layer1: gates = [h1_{s-1} | h2_{s-2}] @ [Wih1 | Whh1]^T ----
        #pragma unroll
        for (int c = 0; c < 4; ++c) {
          f16x8 a[8];
          #pragma unroll
          for (int u = 0; u < 8; ++u) {
            const int kk = (c * 8 + u) * 32 + kq;
            a[u] = (c < 2)
                ? *reinterpret_cast<const f16x8*>(h1r + row * HH + kk)
                : *reinterpret_cast<const f16x8*>(h2r + row * HH + (kk - HH));
          }
          #pragma unroll
          for (int u = 0; u < 8; ++u) {
            const int kk = (c * 8 + u) * 32 + kq;
            f16x8 b0 = *reinterpret_cast<const f16x8*>(&W1s[col0 * PAD1 + kk]);
            f16x8 b1 = *reinterpret_cast<const f16x8*>(&W1s[(16 + col0) * PAD1 + kk]);
            acc0 = __builtin_amdgcn_mfma_f32_16x16x32_f16(a[u], b0, acc0, 0, 0, 0);
            acc1 = __builtin_amdgcn_mfma_f32_16x16x32_f16(a[u], b1, acc1, 0, 0, 0);
          }
        }
      }

      // ---- LSTM cell (frag0 = [i|f], frag1 = [g|o]) ----
      float res[4];
      #pragma unroll
      for (int j = 0; j < 4; j++) {
        float v0 = acc0[j] + bias[0];
        float v1 = acc1[j] + bias[1];
        float p0 = __shfl_xor(v0, 8, 64);
        float p1 = __shfl_xor(v1, 8, 64);
        float ip = low ? v0 : p0;
        float fp = low ? p0 : v0;
        float gp = low ? v1 : p1;
        float op = low ? p1 : v1;
        float cn = sigmoidf_(fp) * cst[j] + sigmoidf_(ip) * tanhf_(gp);
        cst[j] = cn;
        res[j] = sigmoidf_(op) * tanhf_(cn);
      }
      if (low) {
        f16* hw = isL1 ? h2w : h1w;
        const int rowb = wrow + ((lane >> 4) << 2);
        #pragma unroll
        for (int j = 0; j < 4; j++)
          hw[(rowb + j) * HH + hcol] = (f16)res[j];
      }
    }

    // ---- grid barrier: 2-level tree, relaxed spin + final acquire ----
    __syncthreads();
    if (tid == 0) {
      int gen = __hip_atomic_load(genp, __ATOMIC_RELAXED, __HIP_MEMORY_SCOPE_AGENT);
      int p = __hip_atomic_fetch_add(grp, 1, __ATOMIC_ACQ_REL, __HIP_MEMORY_SCOPE_AGENT);
      if (p == 15) {
        __hip_atomic_store(grp, 0, __ATOMIC_RELAXED, __HIP_MEMORY_SCOPE_AGENT);
        int q = __hip_atomic_fetch_add(glob, 1, __ATOMIC_ACQ_REL, __HIP_MEMORY_SCOPE_AGENT);
        if (q == 7) {
          __hip_atomic_store(glob, 0, __ATOMIC_RELAXED, __HIP_MEMORY_SCOPE_AGENT);
          __hip_atomic_fetch_add(genp, 1, __ATOMIC_RELEASE, __HIP_MEMORY_SCOPE_AGENT);
        }
      }
      while (__hip_atomic_load(genp, __ATOMIC_RELAXED, __HIP_MEMORY_SCOPE_AGENT) == gen)
        __builtin_amdgcn_s_sleep(1);
      (void)__hip_atomic_load(genp, __ATOMIC_ACQUIRE, __HIP_MEMORY_SCOPE_AGENT);
    }
    __syncthreads();
  }
}

__global__ void fc1_kernel(const f16* __restrict__ last, const float* __restrict__ w,
                           const float* __restrict__ b, float* __restrict__ z) {
  const int bb = blockIdx.x;   // batch row
  const int j  = threadIdx.x;  // 0..255 output col
  const f16*   lp = last + bb * HH;
  const float* wp = w + j * HH;
  float s = b[j];
  #pragma unroll 8
  for (int k = 0; k < HH; k++) s += (float)lp[k] * wp[k];
  z[bb * H2 + j] = fmaxf(s, 0.0f);
}

__global__ void fc2_kernel(const float* __restrict__ z, const float* __restrict__ w,
                           const float* __restrict__ b, float* __restrict__ out) {
  const int bb = threadIdx.x;  // 0..127
  float s = b[0];
  #pragma unroll 8
  for (int k = 0; k < H2; k++) s += z[bb * H2 + k] * w[k];
  out[bb] = s;
}

extern "C" void kernel_launch(void* const* d_in, const int* in_sizes, int n_in,
                              void* d_out, int out_size, void* d_ws, size_t ws_size,
                              hipStream_t stream) {
  const float* x     = (const float*)d_in[0];
  const float* Wih0  = (const float*)d_in[1];
  const float* Whh0  = (const float*)d_in[2];
  const float* bih0  = (const float*)d_in[3];
  const float* bhh0  = (const float*)d_in[4];
  const float* Wih1  = (const float*)d_in[5];
  const float* Whh1  = (const float*)d_in[6];
  const float* bih1  = (const float*)d_in[7];
  const float* bhh1  = (const float*)d_in[8];
  const float* fc1w  = (const float*)d_in[9];
  const float* fc1b  = (const float*)d_in[10];
  const float* fc2w  = (const float*)d_in[11];
  const float* fc2b  = (const float*)d_in[12];

  char* ws = (char*)d_ws;
  int*  bar = (int*)ws;                          // 4096 B barrier region
  f16*  h1  = (f16*)(ws + 4096);                 // 2 x B x H
  f16*  h2  = h1 + 2 * BB * HH;                  // 2 x B x H
  float* z  = (float*)(ws + 4096 + (size_t)4 * BB * HH * sizeof(f16));  // B x H2

  // zero barrier + h buffers (h_{-1} = 0); re-run every replay
  hipMemsetAsync(ws, 0, 4096 + (size_t)4 * BB * HH * sizeof(f16), stream);

  const size_t smem = (size_t)(32 * PAD0 + 32 * PAD1) * sizeof(f16);
  lstm_fused<<<NWG, NTHR, smem, stream>>>(x, Wih0, Whh0, bih0, bhh0,
                                          Wih1, Whh1, bih1, bhh1, bar, h1, h2);

  const f16* last = h2 + ((TT - 1) & 1) * (BB * HH);  // h2_{T-1}
  fc1_kernel<<<BB, 256, 0, stream>>>(last, fc1w, fc1b, z);
  fc2_kernel<<<1, BB, 0, stream>>>(z, fc2w, fc2b, (float*)d_out);
}